// Round 1
// baseline (466.790 us; speedup 1.0000x reference)
//
#include <hip/hip_runtime.h>
#include <math.h>

#define BETA 0.9f
#define THR  1.0f
#define LEAK 0.9f
#define BB   32
#define DIN  1024
#define DOUT 1024

// d_out flat layout (return order): s, E_W2, E_b2, Rh_W2, Rh_b2, g_bar2, r2
#define OFF_S    0
#define OFF_EW   (BB*DOUT)                         // 32768
#define OFF_EB   (OFF_EW + BB*DIN*DOUT)            // 33587200
#define OFF_RHW  (OFF_EB + BB*DOUT)                // 33619968
#define OFF_RHB  (OFF_RHW + BB*DIN*DOUT)           // 67174400
#define OFF_GBAR (OFF_RHB + BB*DOUT)               // 67207168
#define OFF_R2   (OFF_GBAR + BB*DOUT)              // 67239936

// Kernel 1: h = x@W + b, then all per-(b,o) pointwise outputs.
// grid = (DOUT/64, B), block = 256 (= 64 outputs x 4-way K split)
__global__ __launch_bounds__(256) void k1_matmul_pointwise(
    const float* __restrict__ x, const float* __restrict__ W,
    const float* __restrict__ bias, const float* __restrict__ u,
    const float* __restrict__ E_b, const float* __restrict__ Rh_b,
    const float* __restrict__ g_bar, const float* __restrict__ r,
    float* __restrict__ out)
{
    const int batch = blockIdx.y;
    const int obase = blockIdx.x * 64;
    const int t  = threadIdx.x;
    const int o  = t & 63;        // output lane
    const int kc = t >> 6;        // K-chunk 0..3 (one wave per chunk)

    const float* xrow = x + batch * DIN;
    const float* Wp   = W + obase + o;

    float acc = 0.f;
    const int k0 = kc * (DIN / 4);
    #pragma unroll 8
    for (int j = 0; j < DIN / 4; ++j) {
        const int k = k0 + j;
        acc = fmaf(xrow[k], Wp[(long long)k * DOUT], acc);
    }

    __shared__ float red[4][64];
    red[kc][o] = acc;
    __syncthreads();

    if (t < 64) {
        const int idx = batch * DOUT + obase + o;
        const float h  = red[0][o] + red[1][o] + red[2][o] + red[3][o] + bias[obase + o];
        const float un = BETA * u[idx] + h;
        const float s  = 1.f / (1.f + expf(-(un - THR)));
        const float sg = s * (1.f - s);
        const float dsdu = BETA * sg;

        out[OFF_S + idx] = s;

        // E_b chain
        const float eb1  = fmaf(BETA, E_b[idx], 1.f);
        const float dthb = fmaf(dsdu, eb1, sg);
        out[OFF_EB  + idx] = fmaf(BETA, eb1, 1.f);
        out[OFF_RHB + idx] = fmaf(dsdu, Rh_b[idx], dthb);

        // g_bar / r2
        const float rb    = r[batch];
        const float r2    = fmaf(LEAK, rb, 1.f);
        const float ratio = (LEAK * rb) / r2;
        out[OFF_GBAR + idx] = fmaf(ratio, g_bar[idx], (1.f - ratio) * dsdu);
        if (blockIdx.x == 0 && o == 0) out[OFF_R2 + batch] = r2;
    }
}

// Kernel 2: the 32M-element trace update over (B, DIN, DOUT).
// grid = B*DIN blocks (one per (b,i) row), block = 256 threads, float4 per thread.
__global__ __launch_bounds__(256) void k2_traces(
    const float* __restrict__ x, const float* __restrict__ E_W,
    const float* __restrict__ Rh_W, float* __restrict__ out)
{
    const long long row   = blockIdx.x;       // b*DIN + i
    const int       batch = (int)(row >> 10); // / DIN
    const int       t     = threadIdx.x;

    const float xv = x[row];                  // broadcast scalar per block

    // recompute sg from s (written by k1 into out[OFF_S..])
    const float4 s4 = ((const float4*)(out + OFF_S + (long long)batch * DOUT))[t];

    const long long roff = row * DOUT;
    const float4 ew = ((const float4*)(E_W  + roff))[t];
    const float4 rh = ((const float4*)(Rh_W + roff))[t];

    float4 ew2, rh2;
    {
        const float sg = s4.x * (1.f - s4.x), dsdu = BETA * sg;
        const float e1  = fmaf(BETA, ew.x, xv);
        const float dth = fmaf(dsdu, e1, xv * sg);
        ew2.x = fmaf(BETA, e1, xv);
        rh2.x = fmaf(dsdu, rh.x, dth);
    }
    {
        const float sg = s4.y * (1.f - s4.y), dsdu = BETA * sg;
        const float e1  = fmaf(BETA, ew.y, xv);
        const float dth = fmaf(dsdu, e1, xv * sg);
        ew2.y = fmaf(BETA, e1, xv);
        rh2.y = fmaf(dsdu, rh.y, dth);
    }
    {
        const float sg = s4.z * (1.f - s4.z), dsdu = BETA * sg;
        const float e1  = fmaf(BETA, ew.z, xv);
        const float dth = fmaf(dsdu, e1, xv * sg);
        ew2.z = fmaf(BETA, e1, xv);
        rh2.z = fmaf(dsdu, rh.z, dth);
    }
    {
        const float sg = s4.w * (1.f - s4.w), dsdu = BETA * sg;
        const float e1  = fmaf(BETA, ew.w, xv);
        const float dth = fmaf(dsdu, e1, xv * sg);
        ew2.w = fmaf(BETA, e1, xv);
        rh2.w = fmaf(dsdu, rh.w, dth);
    }

    ((float4*)(out + OFF_EW  + roff))[t] = ew2;
    ((float4*)(out + OFF_RHW + roff))[t] = rh2;
}

extern "C" void kernel_launch(void* const* d_in, const int* in_sizes, int n_in,
                              void* d_out, int out_size, void* d_ws, size_t ws_size,
                              hipStream_t stream) {
    const float* x     = (const float*)d_in[0];
    const float* W     = (const float*)d_in[1];
    const float* bias  = (const float*)d_in[2];
    const float* u     = (const float*)d_in[3];
    const float* E_W   = (const float*)d_in[4];
    const float* E_b   = (const float*)d_in[5];
    const float* Rh_W  = (const float*)d_in[6];
    const float* Rh_b  = (const float*)d_in[7];
    const float* g_bar = (const float*)d_in[8];
    const float* r     = (const float*)d_in[9];
    float* out = (float*)d_out;

    dim3 g1(DOUT / 64, BB);
    k1_matmul_pointwise<<<g1, 256, 0, stream>>>(x, W, bias, u, E_b, Rh_b, g_bar, r, out);
    k2_traces<<<BB * DIN, 256, 0, stream>>>(x, E_W, Rh_W, out);
}